// Round 8
// baseline (435.672 us; speedup 1.0000x reference)
//
#include <hip/hip_runtime.h>
#include <hip/hip_bf16.h>

// RGCN 2-layer encoder. N=50000, R=16, B=8, Dim=128, E=625000.
// fp32 in/out (runtime-detected), bf16 MFMA internals.
//
// R23: agg+GEMM fusion. R21/R22 pipeline tuning of fusegemm was neutral
// (MfmaUtil pinned ~9.5%) -> the cost is the Gall round-trip itself
// (agg2: 100MB HBM write; fusegemm: 58MB HBM + ~45MB L3 read). Fused
// kernel aggemm_rg: block = 32 nodes, 512 threads. Phase 1: 8 waves x
// 4 nodes gather (depth-4 readlane loop, unchanged) -> G in LDS
// [9 seg][32][128] bf16 segment-major, XOR-swizzled rows; self slot = x
// tile via global_load_lds w/ pre-swizzled source (rule #21). One barrier.
// Phase 2: 9-segment GEMM from LDS (A never re-staged), B dbuf in regs,
// wave = 32 rows x 16 cols (no B duplication), LN+ReLU epilogue.
// 76KB LDS -> 2 blocks/CU: gather keeps 16 waves/CU and overlaps the
// co-resident block's GEMM phase. Deletes ~160MB HBM traffic + 2
// dispatches per layer. 12 dispatches total.

static constexpr int kDim = 128;
static constexpr int kRel = 16;
static constexpr int kBas = 8;
static constexpr int kSeg = kBas + 1;   // 8 bases + self

typedef __attribute__((ext_vector_type(8))) short bf16x8;
typedef __attribute__((ext_vector_type(4))) float f32x4;

static __device__ __forceinline__ float bf2f_rg(unsigned short h) {
    return __uint_as_float(((unsigned)h) << 16);
}
static __device__ __forceinline__ unsigned short f2bf_rg(float f) {
    unsigned u = __float_as_uint(f);
    u = u + 0x7fffu + ((u >> 16) & 1u);   // round-to-nearest-even
    return (unsigned short)(u >> 16);
}

static __device__ __forceinline__ void gload_lds16(const void* g, void* l) {
    __builtin_amdgcn_global_load_lds(
        (const __attribute__((address_space(1))) unsigned*)g,
        (__attribute__((address_space(3))) unsigned*)l, 16, 0, 0);
}

// dtype flag from emb's first 128 halves (call with one full wave, tid<64):
// any bf16-decoded exponent >= 0x86 (|v|>=128/inf/nan) => input is fp32
static __device__ __forceinline__ int flag_from(const unsigned short* x, int lane) {
    unsigned e0 = ((unsigned)x[lane] >> 7) & 0xFFu;
    unsigned e1 = ((unsigned)x[lane + 64] >> 7) & 0xFFu;
    int bad = (e0 >= 0x86u) || (e1 >= 0x86u);
    return (__ballot(bad) != 0ull) ? 1 : 0;
}

// template-named kernel: sentinel stub (d_out fully overwritten by pipeline)
__global__ void RGCNEncoder_89962384982025_kernel(unsigned* p, int n) {
    int i = blockIdx.x * 256 + threadIdx.x;
    if (i < n) p[i] = 0x3F803F80u;
}

// convert emb (fp32 or bf16, flag derived inline) -> bf16 xin
__global__ void cvt_rg(const void* xraw, unsigned short* xout, int n) {
    __shared__ int fsh;
    if (threadIdx.x < 64) {
        int fl = flag_from((const unsigned short*)xraw, threadIdx.x);
        if (threadIdx.x == 0) fsh = fl;
    }
    __syncthreads();
    int f = fsh;
    int i = blockIdx.x * 256 + threadIdx.x;
    if (i >= n) return;
    if (f)
        xout[i] = f2bf_rg(((const float*)xraw)[i]);
    else
        xout[i] = ((const unsigned short*)xraw)[i];
}

__global__ void zero_rg(int* p, int n) {
    int i = blockIdx.x * 256 + threadIdx.x;
    if (i < n) p[i] = 0;
}

__global__ void count_rg(const int* ei, const int* et, int* cnt, int E) {
    int e = blockIdx.x * 256 + threadIdx.x;
    if (e < E) atomicAdd(&cnt[ei[e] * kRel + et[e]], 1);
}

// hierarchical scan, in place on rowptr (saves the incl buffer)
__global__ void scanA_rg(const int* cnt, int* rowptr, int* bsum, int n) {
    __shared__ int sh[256];
    int tid = threadIdx.x;
    int i = blockIdx.x * 256 + tid;
    int v = (i < n) ? cnt[i] : 0;
    sh[tid] = v;
    __syncthreads();
    for (int off = 1; off < 256; off <<= 1) {
        int t = (tid >= off) ? sh[tid - off] : 0;
        __syncthreads();
        sh[tid] += t;
        __syncthreads();
    }
    if (i < n) rowptr[i + 1] = sh[tid];
    if (tid == 255) bsum[blockIdx.x] = sh[255];
}
__global__ void scanB_rg(int* bsum, int nb) {
    __shared__ int partial[256];
    int tid = threadIdx.x;
    int chunk = (nb + 255) / 256;
    int s0 = tid * chunk;
    int s1 = min(s0 + chunk, nb);
    int sum = 0;
    for (int i = s0; i < s1; ++i) sum += bsum[i];
    partial[tid] = sum;
    __syncthreads();
    for (int off = 1; off < 256; off <<= 1) {
        int t = (tid >= off) ? partial[tid - off] : 0;
        __syncthreads();
        partial[tid] += t;
        __syncthreads();
    }
    int run = (tid == 0) ? 0 : partial[tid - 1];
    for (int i = s0; i < s1; ++i) { int v = bsum[i]; bsum[i] = run; run += v; }
}
__global__ void scanC_rg(int* rowptr, const int* bsum, int n) {
    int i = blockIdx.x * 256 + threadIdx.x;
    if (i < n) rowptr[i + 1] += bsum[blockIdx.x];
    if (i == 0) rowptr[0] = 0;
}

// fill: pcols entry packs col | rel<<26 (col < 2^26)
__global__ void fill_rg(const int* ei, const int* et, const int* rowptr,
                        int* cnt, int* pcols, int E) {
    int e = blockIdx.x * 256 + threadIdx.x;
    if (e < E) {
        int rel = et[e];
        int key = ei[e] * kRel + rel;
        int old = atomicSub(&cnt[key], 1);
        pcols[rowptr[key] + old - 1] = ei[E + e] | (rel << 26);
    }
}

// wallT[b][o][k] = bases[b][k][o] for b<8; slot 8 = selfw^T.
// Also stages coef decoded to fp32 (coefw[16][8]) for the LDS mix table.
__global__ void wall_rg(const void* bases, const void* coef, const void* selfw,
                        const unsigned short* emb, unsigned short* wallT,
                        float* coefw) {
    __shared__ int fsh;
    if (threadIdx.x < 64) {
        int fl = flag_from(emb, threadIdx.x);
        if (threadIdx.x == 0) fsh = fl;
    }
    __syncthreads();
    int f = fsh;
    int idx = blockIdx.x * 256 + threadIdx.x;   // b*16384 + o*128 + k
    int b = idx >> 14;
    int o = (idx >> 7) & 127;
    int k = idx & 127;
    if (blockIdx.x == 0 && threadIdx.x < kRel * kBas) {
        coefw[threadIdx.x] = f ? ((const float*)coef)[threadIdx.x]
                               : bf2f_rg(((const unsigned short*)coef)[threadIdx.x]);
    }
    if (b < kBas) {
        float bv = f ? ((const float*)bases)[b * 16384 + k * 128 + o]
                     : bf2f_rg(((const unsigned short*)bases)[b * 16384 + k * 128 + o]);
        wallT[idx] = f2bf_rg(bv);
    } else {
        float sv = f ? ((const float*)selfw)[k * 128 + o]
                     : bf2f_rg(((const unsigned short*)selfw)[k * 128 + o]);
        wallT[idx] = f2bf_rg(sv);
    }
}

// Fused aggregate+GEMM+LN+ReLU. Block = 32 nodes, 512 threads (8 waves).
// Phase 1: wave wv gathers nodes m0+wv*4..+3 (depth-4 readlane loop),
//   basis-mixes into g0/g1[8], ds_writes G[b][ln][*] (XOR-swizzled rows);
//   x tile staged into G[8] (self slot) via gload_lds w/ pre-swizzled src.
// Phase 2: out[n][o] = sum_seg G[seg][n][:] @ wallT[seg][o][:], wave =
//   32 rows x 16 cols (col = wave*16+lrow), B dbuf in regs; LN+ReLU.
// C map (m89/m91): col=lane&15, row=(lane>>4)*4+reg.
__global__ __launch_bounds__(512, 4) void aggemm_rg(const int* rowptr2, const int* pcols,
                                                    const unsigned short* xsrc,
                                                    const unsigned short* wallT,
                                                    const float* coefw,
                                                    const void* bias, const void* gw,
                                                    const void* bw,
                                                    const unsigned short* emb,
                                                    unsigned short* out_b, float* out_f,
                                                    int ofp32, int M) {
    __shared__ __align__(16) unsigned short G[kSeg][32][128];  // 73.7KB, swizzled
    __shared__ float csh[kRel * kBas];
    __shared__ float pS[32][8];
    __shared__ float pQ[32][8];
    __shared__ float mrs[32][2];
    __shared__ int fsh;
    const int tid = threadIdx.x;
    const int wave = tid >> 6;
    const int lane = tid & 63;
    const int m0 = blockIdx.x * 32;
    if (tid < 64) {
        int fl = flag_from(emb, tid);
        if (tid == 0) fsh = fl;
    }
    if (tid < kRel * kBas) csh[tid] = coefw[tid];

    // x tile -> G[kBas] (self slot) via gload_lds, pre-swizzled source.
    // gi=tid: row=gi>>4 (32 rows x 16 slots), LDS dest linear (wave-contig).
    {
        int row = tid >> 4;
        int c = ((tid & 15) << 4) ^ ((row & 7) << 4);
        int gr = m0 + row;
        if (gr > M - 1) gr = M - 1;
        gload_lds16((const char*)xsrc + (size_t)gr * 256 + c,
                    &G[kBas][0][0] + tid * 8);
    }
    __syncthreads();   // csh ready (gather uses it); vm drain folded here too

    // ---- Phase 1: gather 4 nodes per wave ----
    const int ln0 = wave * 4;
    for (int j = 0; j < 4; ++j) {
        int ln = ln0 + j;
        int n = m0 + ln;
        if (n >= M) break;
        const int s = rowptr2[n * kRel];
        const int e = rowptr2[n * kRel + kRel];
        const unsigned short* xl = xsrc + 2 * lane;
        float g0[kBas], g1[kBas];
#pragma unroll
        for (int b = 0; b < kBas; ++b) { g0[b] = 0.f; g1[b] = 0.f; }
        float s0 = 0.f, s1 = 0.f;
        int cur = -1, cnt = 0;
        auto flush = [&]() {
            float w = __builtin_amdgcn_rcpf((float)cnt);
            float t0 = s0 * w, t1 = s1 * w;
            const float* cr = csh + cur * kBas;
#pragma unroll
            for (int b = 0; b < kBas; ++b) {
                float c = cr[b];
                g0[b] += c * t0;
                g1[b] += c * t1;
            }
            s0 = 0.f; s1 = 0.f; cnt = 0;
        };
        for (int base = s; base < e; base += 64) {
            int m = e - base;
            if (m > 64) m = 64;
            int pk = 0;
            if (base + lane < e) pk = pcols[base + lane];
            int i = 0;
            for (; i + 4 <= m; i += 4) {
                int v0 = __builtin_amdgcn_readlane(pk, i);
                int v1 = __builtin_amdgcn_readlane(pk, i + 1);
                int v2 = __builtin_amdgcn_readlane(pk, i + 2);
                int v3 = __builtin_amdgcn_readlane(pk, i + 3);
                unsigned u0 = *(const unsigned*)(xl + (size_t)(v0 & 0x03FFFFFF) * 128);
                unsigned u1 = *(const unsigned*)(xl + (size_t)(v1 & 0x03FFFFFF) * 128);
                unsigned u2 = *(const unsigned*)(xl + (size_t)(v2 & 0x03FFFFFF) * 128);
                unsigned u3 = *(const unsigned*)(xl + (size_t)(v3 & 0x03FFFFFF) * 128);
                int r0 = (int)((unsigned)v0 >> 26);
                int r1 = (int)((unsigned)v1 >> 26);
                int r2 = (int)((unsigned)v2 >> 26);
                int r3 = (int)((unsigned)v3 >> 26);
                if (r0 != cur) { if (cnt) flush(); cur = r0; }
                s0 += __uint_as_float(u0 << 16); s1 += __uint_as_float(u0 & 0xffff0000u); ++cnt;
                if (r1 != cur) { flush(); cur = r1; }
                s0 += __uint_as_float(u1 << 16); s1 += __uint_as_float(u1 & 0xffff0000u); ++cnt;
                if (r2 != cur) { flush(); cur = r2; }
                s0 += __uint_as_float(u2 << 16); s1 += __uint_as_float(u2 & 0xffff0000u); ++cnt;
                if (r3 != cur) { flush(); cur = r3; }
                s0 += __uint_as_float(u3 << 16); s1 += __uint_as_float(u3 & 0xffff0000u); ++cnt;
            }
            for (; i < m; ++i) {
                int v = __builtin_amdgcn_readlane(pk, i);
                unsigned u = *(const unsigned*)(xl + (size_t)(v & 0x03FFFFFF) * 128);
                int rel = (int)((unsigned)v >> 26);
                if (rel != cur) { if (cnt) flush(); cur = rel; }
                s0 += __uint_as_float(u << 16);
                s1 += __uint_as_float(u & 0xffff0000u);
                ++cnt;
            }
        }
        if (cnt) flush();
        // write G rows (swizzled: byte (lane*4) ^ ((ln&7)<<4); bijective/row)
        int byteoff = (lane * 4) ^ ((ln & 7) << 4);
#pragma unroll
        for (int b = 0; b < kBas; ++b) {
            unsigned outp = (unsigned)f2bf_rg(g0[b]) | ((unsigned)f2bf_rg(g1[b]) << 16);
            *(unsigned*)((char*)&G[b][0][0] + ln * 256 + byteoff) = outp;
        }
    }
    __syncthreads();   // G complete (incl. x slot: barrier drains vmcnt)

    // ---- Phase 2: GEMM from LDS, B dbuf in regs ----
    const int lrow = lane & 15;
    const int lq = lane >> 4;
    const int col = wave * 16 + lrow;    // this lane's output column
    f32x4 acc[2] = {};
    bf16x8 breg[2][4];
    auto loadB = [&](int seg, bf16x8 (&b)[4]) {
        const unsigned short* Bsrc = wallT + (size_t)seg * 16384 + (size_t)col * 128;
#pragma unroll
        for (int kk4 = 0; kk4 < 4; ++kk4)
            b[kk4] = *(const bf16x8*)(Bsrc + kk4 * 32 + lq * 8);
    };
    loadB(0, breg[0]);
#pragma unroll
    for (int seg = 0; seg < kSeg; ++seg) {
        if (seg + 1 < kSeg) loadB(seg + 1, breg[(seg + 1) & 1]);
#pragma unroll
        for (int kk4 = 0; kk4 < 4; ++kk4) {
#pragma unroll
            for (int mt = 0; mt < 2; ++mt) {
                int r = mt * 16 + lrow;
                int cb = (kk4 * 64 + lq * 16) ^ ((r & 7) << 4);
                bf16x8 a = *(const bf16x8*)((const char*)&G[seg][0][0] + r * 256 + cb);
                acc[mt] = __builtin_amdgcn_mfma_f32_16x16x32_bf16(
                    a, breg[seg & 1][kk4], acc[mt], 0, 0, 0);
            }
        }
    }

    // ---- epilogue: +bias, LN (row stats across 8 col-waves), ReLU ----
    const int f = fsh;
    float bv, gv, betav;
    if (f) {
        bv = ((const float*)bias)[col];
        gv = ((const float*)gw)[col];
        betav = ((const float*)bw)[col];
    } else {
        bv = bf2f_rg(((const unsigned short*)bias)[col]);
        gv = bf2f_rg(((const unsigned short*)gw)[col]);
        betav = bf2f_rg(((const unsigned short*)bw)[col]);
    }
#pragma unroll
    for (int mt = 0; mt < 2; ++mt)
#pragma unroll
        for (int i = 0; i < 4; ++i) {
            float v = acc[mt][i] + bv;
            acc[mt][i] = v;
            float sv = v, qv = v * v;
            for (int o = 1; o < 16; o <<= 1) {
                sv += __shfl_xor(sv, o);
                qv += __shfl_xor(qv, o);
            }
            if (lrow == 0) {
                int row = mt * 16 + lq * 4 + i;
                pS[row][wave] = sv;
                pQ[row][wave] = qv;
            }
        }
    __syncthreads();
    if (tid < 32) {
        float s8 = 0.f, q8 = 0.f;
#pragma unroll
        for (int w = 0; w < 8; ++w) { s8 += pS[tid][w]; q8 += pQ[tid][w]; }
        float mean = s8 * (1.0f / 128.0f);
        float var = q8 * (1.0f / 128.0f) - mean * mean;
        mrs[tid][0] = mean;
        mrs[tid][1] = rsqrtf(var + 1e-5f);
    }
    __syncthreads();
#pragma unroll
    for (int mt = 0; mt < 2; ++mt)
#pragma unroll
        for (int i = 0; i < 4; ++i) {
            int row = mt * 16 + lq * 4 + i;
            int gr = m0 + row;
            if (gr < M) {
                float o = fmaxf((acc[mt][i] - mrs[row][0]) * mrs[row][1] * gv + betav, 0.f);
                if (ofp32)
                    out_f[(size_t)gr * 128 + col] = o;
                else
                    out_b[(size_t)gr * 128 + col] = f2bf_rg(o);
            }
        }
}

extern "C" void kernel_launch(void* const* d_in, const int* in_sizes, int n_in,
                              void* d_out, int out_size, void* d_ws, size_t ws_size,
                              hipStream_t stream) {
    const int* ei = (const int*)d_in[0];            // [2,E] int32
    const int* et = (const int*)d_in[1];            // [E] int32
    const void* emb    = d_in[2];
    const void* bases1 = d_in[3];
    const void* coef1  = d_in[4];
    const void* selfw1 = d_in[5];
    const void* bias1  = d_in[6];
    const void* g1     = d_in[7];
    const void* b1     = d_in[8];
    const void* bases2 = d_in[9];
    const void* coef2  = d_in[10];
    const void* selfw2 = d_in[11];
    const void* bias2  = d_in[12];
    const void* g2     = d_in[13];
    const void* b2     = d_in[14];

    const int E = in_sizes[1];
    const int N = out_size / kDim;
    const int n16 = N * kRel;
    const int nsb = (n16 + 255) / 256;

    // workspace (256B-aligned). No Gall anymore (G lives in LDS).
    char* ws = (char*)d_ws;
    size_t off = 0;
    float* coefw = (float*)(ws + off); off += 512;
    int* rowptr2 = (int*)(ws + off); off += (((size_t)n16 + 1) * 4 + 255) & ~(size_t)255;
    int* cnt     = (int*)(ws + off); off += ((size_t)n16 * 4 + 255) & ~(size_t)255;
    int* bsum    = (int*)(ws + off); off += ((size_t)nsb * 4 + 255) & ~(size_t)255;
    int* pcols   = (int*)(ws + off); off += ((size_t)E * 4 + 255) & ~(size_t)255;
    unsigned short* wallT = (unsigned short*)(ws + off);
    off += ((size_t)kSeg * 16384 * 2 + 255) & ~(size_t)255;
    unsigned short* xin  = (unsigned short*)(ws + off);
    off += ((size_t)N * 128 * 2 + 255) & ~(size_t)255;
    unsigned short* xmid = (unsigned short*)(ws + off);
    (void)n_in; (void)ws_size;

    const int eblk = (E + 255) / 256;
    const int mblk32 = (N + 31) / 32;
    const int nelem = N * 128;
    const unsigned short* embh = (const unsigned short*)emb;

    // sentinel stub (template symbol; d_out fully overwritten by layer 2)
    RGCNEncoder_89962384982025_kernel<<<1, 256, 0, stream>>>((unsigned*)d_out, 256);

    // emb -> bf16 (dtype flag derived inline)
    cvt_rg<<<(nelem + 255) / 256, 256, 0, stream>>>(emb, xin, nelem);

    // CSR by (node, relation); in-place hierarchical scan
    zero_rg<<<(n16 + 255) / 256, 256, 0, stream>>>(cnt, n16);
    count_rg<<<eblk, 256, 0, stream>>>(ei, et, cnt, E);
    scanA_rg<<<nsb, 256, 0, stream>>>(cnt, rowptr2, bsum, n16);
    scanB_rg<<<1, 256, 0, stream>>>(bsum, nsb);
    scanC_rg<<<nsb, 256, 0, stream>>>(rowptr2, bsum, n16);
    fill_rg<<<eblk, 256, 0, stream>>>(ei, et, rowptr2, cnt, pcols, E);

    // layer 1: fused agg+GEMM -> bf16 xmid
    wall_rg<<<kSeg * 64, 256, 0, stream>>>(bases1, coef1, selfw1, embh, wallT, coefw);
    aggemm_rg<<<mblk32, 512, 0, stream>>>(rowptr2, pcols, xin, wallT, coefw,
                                          bias1, g1, b1, embh,
                                          xmid, (float*)nullptr, 0, N);

    // layer 2: fused agg+GEMM -> fp32 d_out
    wall_rg<<<kSeg * 64, 256, 0, stream>>>(bases2, coef2, selfw2, embh, wallT, coefw);
    aggemm_rg<<<mblk32, 512, 0, stream>>>(rowptr2, pcols, xmid, wallT, coefw,
                                          bias2, g2, b2, embh,
                                          (unsigned short*)nullptr, (float*)d_out,
                                          1, N);
}

// Round 9
// 406.924 us; speedup vs baseline: 1.0706x; 1.0706x over previous
//
#include <hip/hip_runtime.h>
#include <hip/hip_bf16.h>

// RGCN 2-layer encoder. N=50000, R=16, B=8, Dim=128, E=625000.
// fp32 in/out (runtime-detected), bf16 MFMA internals.
//
// R24: revert R23's agg+GEMM fusion (regressed: gather lost TLP to the
// 76KB-LDS 2-block/CU occupancy floor). Back to R21 split structure;
// fusegemm re-tiled 64->32 rows: R21's counters (MfmaUtil 9.5%, VALU 9.5%,
// HBM 16%, Occ 23%) are the latency/OCCUPANCY signature — grid was only
// 782 blocks (3/CU). 32-row tile -> 1563 blocks (6.1/CU), LDS 16KB,
// __launch_bounds__(256,6). B-before-stage vmcnt ordering, both-sides
// XOR swizzle, 2-phase dbuf all unchanged (verified at R21).
//
// Pipeline per layer: wallT[b][o][k]=bases[b]^T (slot8=selfw^T) + coefw fp32;
// agg2: wave-per-node CSR scan -> Gall[n][b*128+o] (basis space, 102MB);
// fusegemm: out[n][o] = [Gall[n] | x[n]] @ wallT (K=1152), epilogue LN+ReLU.

static constexpr int kDim = 128;
static constexpr int kRel = 16;
static constexpr int kBas = 8;
static constexpr int kSeg = kBas + 1;   // 8 bases + self

typedef __attribute__((ext_vector_type(8))) short bf16x8;
typedef __attribute__((ext_vector_type(4))) float f32x4;

static __device__ __forceinline__ float bf2f_rg(unsigned short h) {
    return __uint_as_float(((unsigned)h) << 16);
}
static __device__ __forceinline__ unsigned short f2bf_rg(float f) {
    unsigned u = __float_as_uint(f);
    u = u + 0x7fffu + ((u >> 16) & 1u);   // round-to-nearest-even
    return (unsigned short)(u >> 16);
}

static __device__ __forceinline__ void gload_lds16(const void* g, void* l) {
    __builtin_amdgcn_global_load_lds(
        (const __attribute__((address_space(1))) unsigned*)g,
        (__attribute__((address_space(3))) unsigned*)l, 16, 0, 0);
}

// dtype flag from emb's first 128 halves (call with one full wave, tid<64):
// any bf16-decoded exponent >= 0x86 (|v|>=128/inf/nan) => input is fp32
static __device__ __forceinline__ int flag_from(const unsigned short* x, int lane) {
    unsigned e0 = ((unsigned)x[lane] >> 7) & 0xFFu;
    unsigned e1 = ((unsigned)x[lane + 64] >> 7) & 0xFFu;
    int bad = (e0 >= 0x86u) || (e1 >= 0x86u);
    return (__ballot(bad) != 0ull) ? 1 : 0;
}

// template-named kernel: sentinel stub (d_out fully overwritten by pipeline)
__global__ void RGCNEncoder_89962384982025_kernel(unsigned* p, int n) {
    int i = blockIdx.x * 256 + threadIdx.x;
    if (i < n) p[i] = 0x3F803F80u;
}

// convert emb (fp32 or bf16, flag derived inline) -> bf16 xin
__global__ void cvt_rg(const void* xraw, unsigned short* xout, int n) {
    __shared__ int fsh;
    if (threadIdx.x < 64) {
        int fl = flag_from((const unsigned short*)xraw, threadIdx.x);
        if (threadIdx.x == 0) fsh = fl;
    }
    __syncthreads();
    int f = fsh;
    int i = blockIdx.x * 256 + threadIdx.x;
    if (i >= n) return;
    if (f)
        xout[i] = f2bf_rg(((const float*)xraw)[i]);
    else
        xout[i] = ((const unsigned short*)xraw)[i];
}

__global__ void zero_rg(int* p, int n) {
    int i = blockIdx.x * 256 + threadIdx.x;
    if (i < n) p[i] = 0;
}

__global__ void count_rg(const int* ei, const int* et, int* cnt, int E) {
    int e = blockIdx.x * 256 + threadIdx.x;
    if (e < E) atomicAdd(&cnt[ei[e] * kRel + et[e]], 1);
}

// hierarchical scan, in place on rowptr (saves the incl buffer)
__global__ void scanA_rg(const int* cnt, int* rowptr, int* bsum, int n) {
    __shared__ int sh[256];
    int tid = threadIdx.x;
    int i = blockIdx.x * 256 + tid;
    int v = (i < n) ? cnt[i] : 0;
    sh[tid] = v;
    __syncthreads();
    for (int off = 1; off < 256; off <<= 1) {
        int t = (tid >= off) ? sh[tid - off] : 0;
        __syncthreads();
        sh[tid] += t;
        __syncthreads();
    }
    if (i < n) rowptr[i + 1] = sh[tid];
    if (tid == 255) bsum[blockIdx.x] = sh[255];
}
__global__ void scanB_rg(int* bsum, int nb) {
    __shared__ int partial[256];
    int tid = threadIdx.x;
    int chunk = (nb + 255) / 256;
    int s0 = tid * chunk;
    int s1 = min(s0 + chunk, nb);
    int sum = 0;
    for (int i = s0; i < s1; ++i) sum += bsum[i];
    partial[tid] = sum;
    __syncthreads();
    for (int off = 1; off < 256; off <<= 1) {
        int t = (tid >= off) ? partial[tid - off] : 0;
        __syncthreads();
        partial[tid] += t;
        __syncthreads();
    }
    int run = (tid == 0) ? 0 : partial[tid - 1];
    for (int i = s0; i < s1; ++i) { int v = bsum[i]; bsum[i] = run; run += v; }
}
__global__ void scanC_rg(int* rowptr, const int* bsum, int n) {
    int i = blockIdx.x * 256 + threadIdx.x;
    if (i < n) rowptr[i + 1] += bsum[blockIdx.x];
    if (i == 0) rowptr[0] = 0;
}

// fill: pcols entry packs col | rel<<26 (col < 2^26)
__global__ void fill_rg(const int* ei, const int* et, const int* rowptr,
                        int* cnt, int* pcols, int E) {
    int e = blockIdx.x * 256 + threadIdx.x;
    if (e < E) {
        int rel = et[e];
        int key = ei[e] * kRel + rel;
        int old = atomicSub(&cnt[key], 1);
        pcols[rowptr[key] + old - 1] = ei[E + e] | (rel << 26);
    }
}

// wallT[b][o][k] = bases[b][k][o] for b<8; slot 8 = selfw^T.
// Also stages coef decoded to fp32 (coefw[16][8]) for agg2's LDS mix table.
__global__ void wall_rg(const void* bases, const void* coef, const void* selfw,
                        const unsigned short* emb, unsigned short* wallT,
                        float* coefw) {
    __shared__ int fsh;
    if (threadIdx.x < 64) {
        int fl = flag_from(emb, threadIdx.x);
        if (threadIdx.x == 0) fsh = fl;
    }
    __syncthreads();
    int f = fsh;
    int idx = blockIdx.x * 256 + threadIdx.x;   // b*16384 + o*128 + k
    int b = idx >> 14;
    int o = (idx >> 7) & 127;
    int k = idx & 127;
    if (blockIdx.x == 0 && threadIdx.x < kRel * kBas) {
        coefw[threadIdx.x] = f ? ((const float*)coef)[threadIdx.x]
                               : bf2f_rg(((const unsigned short*)coef)[threadIdx.x]);
    }
    if (b < kBas) {
        float bv = f ? ((const float*)bases)[b * 16384 + k * 128 + o]
                     : bf2f_rg(((const unsigned short*)bases)[b * 16384 + k * 128 + o]);
        wallT[idx] = f2bf_rg(bv);
    } else {
        float sv = f ? ((const float*)selfw)[k * 128 + o]
                     : bf2f_rg(((const unsigned short*)selfw)[k * 128 + o]);
        wallT[idx] = f2bf_rg(sv);
    }
}

// aggregate-first in basis space: Gall[n][b*128+o] = sum_r coefw[r][b] *
// mean over r-bucket edges of x[col][o]. Wave per node (4 waves/block).
// Depth-4 batched gather: 4 readlanes + 4 independent loads in flight,
// then bucket-transition logic on the returned values (latency overlap).
__global__ __launch_bounds__(256) void agg2_rg(const int* rowptr2, const int* pcols,
                                               const unsigned short* xsrc,
                                               const float* coefw,
                                               unsigned short* Gall, int N) {
    __shared__ float csh[kRel * kBas];
    if (threadIdx.x < kRel * kBas) csh[threadIdx.x] = coefw[threadIdx.x];
    __syncthreads();
    int wv = threadIdx.x >> 6;
    int lane = threadIdx.x & 63;
    int n = blockIdx.x * 4 + wv;
    if (n >= N) return;
    const int s = rowptr2[n * kRel];          // wave-uniform -> scalar load
    const int e = rowptr2[n * kRel + kRel];
    const unsigned short* xl = xsrc + 2 * lane;
    float g0[kBas], g1[kBas];
#pragma unroll
    for (int b = 0; b < kBas; ++b) { g0[b] = 0.f; g1[b] = 0.f; }
    float s0 = 0.f, s1 = 0.f;
    int cur = -1, cnt = 0;
    auto flush = [&]() {
        float w = __builtin_amdgcn_rcpf((float)cnt);
        float t0 = s0 * w, t1 = s1 * w;
        const float* cr = csh + cur * kBas;
#pragma unroll
        for (int b = 0; b < kBas; ++b) {
            float c = cr[b];                  // broadcast ds_read
            g0[b] += c * t0;
            g1[b] += c * t1;
        }
        s0 = 0.f; s1 = 0.f; cnt = 0;
    };
    for (int base = s; base < e; base += 64) {
        int m = e - base;
        if (m > 64) m = 64;
        int pk = 0;
        if (base + lane < e) pk = pcols[base + lane];
        int i = 0;
        for (; i + 4 <= m; i += 4) {
            // issue 4 independent gathers back-to-back (4 in flight)
            int v0 = __builtin_amdgcn_readlane(pk, i);
            int v1 = __builtin_amdgcn_readlane(pk, i + 1);
            int v2 = __builtin_amdgcn_readlane(pk, i + 2);
            int v3 = __builtin_amdgcn_readlane(pk, i + 3);
            unsigned u0 = *(const unsigned*)(xl + (size_t)(v0 & 0x03FFFFFF) * 128);
            unsigned u1 = *(const unsigned*)(xl + (size_t)(v1 & 0x03FFFFFF) * 128);
            unsigned u2 = *(const unsigned*)(xl + (size_t)(v2 & 0x03FFFFFF) * 128);
            unsigned u3 = *(const unsigned*)(xl + (size_t)(v3 & 0x03FFFFFF) * 128);
            int r0 = (int)((unsigned)v0 >> 26);
            int r1 = (int)((unsigned)v1 >> 26);
            int r2 = (int)((unsigned)v2 >> 26);
            int r3 = (int)((unsigned)v3 >> 26);
            if (r0 != cur) { if (cnt) flush(); cur = r0; }
            s0 += __uint_as_float(u0 << 16); s1 += __uint_as_float(u0 & 0xffff0000u); ++cnt;
            if (r1 != cur) { flush(); cur = r1; }
            s0 += __uint_as_float(u1 << 16); s1 += __uint_as_float(u1 & 0xffff0000u); ++cnt;
            if (r2 != cur) { flush(); cur = r2; }
            s0 += __uint_as_float(u2 << 16); s1 += __uint_as_float(u2 & 0xffff0000u); ++cnt;
            if (r3 != cur) { flush(); cur = r3; }
            s0 += __uint_as_float(u3 << 16); s1 += __uint_as_float(u3 & 0xffff0000u); ++cnt;
        }
        for (; i < m; ++i) {
            int v = __builtin_amdgcn_readlane(pk, i);
            unsigned u = *(const unsigned*)(xl + (size_t)(v & 0x03FFFFFF) * 128);
            int rel = (int)((unsigned)v >> 26);
            if (rel != cur) { if (cnt) flush(); cur = rel; }
            s0 += __uint_as_float(u << 16);
            s1 += __uint_as_float(u & 0xffff0000u);
            ++cnt;
        }
    }
    if (cnt) flush();
    unsigned short* grow = Gall + (size_t)n * (kBas * 128) + 2 * lane;
#pragma unroll
    for (int b = 0; b < kBas; ++b) {
        unsigned outp = (unsigned)f2bf_rg(g0[b]) | ((unsigned)f2bf_rg(g1[b]) << 16);
        *(unsigned*)(grow + b * 128) = outp;
    }
}

// fused GEMM: out[n][o] = [Gall[n] (K=1024) | x[n] (K=128)] @ wallT[seg][o][k]
// + bias, then LayerNorm + ReLU in-epilogue. 32-row C-tile (1563 blocks,
// 6.1/CU), 4 waves each owning the full 32 rows x a 32-col slice
// (16x16x32 bf16 MFMA; C map m89/m91: col=lane&15, row=(lane>>4)*4+reg).
// Double-buffered global_load_lds A-tile (16KB) with row-XOR swizzle
// (both-sides); per segment: B-loads FIRST (oldest in vmcnt queue), then
// stage(seg+1), then ds_read+MFMA, then vmcnt(0)+barrier.
__global__ __launch_bounds__(256, 6) void fusegemm_rg(const unsigned short* Gall,
                                                      const unsigned short* x,
                                                      const unsigned short* wallT,
                                                      const void* bias, const void* gw,
                                                      const void* bw,
                                                      const unsigned short* emb,
                                                      unsigned short* out_b, float* out_f,
                                                      int ofp32, int M) {
    __shared__ __align__(16) unsigned short As[2][32][128];   // linear, swizzled
    __shared__ float pS[32][4];
    __shared__ float pQ[32][4];
    __shared__ float mrs[32][2];
    __shared__ int fsh;
    const int m0 = blockIdx.x * 32;
    const int tid = threadIdx.x;
    const int wave = tid >> 6;
    const int lane = tid & 63;
    const int wn = wave * 32;
    const int lrow = lane & 15;
    const int lq = lane >> 4;
    if (tid < 64) {
        int fl = flag_from(emb, tid);
        if (tid == 0) fsh = fl;
    }

    // stage segment seg into As[buf]: 2 x global_load_lds(16B) per thread.
    // granule gi=it*256+tid: row=gi>>4 (32 rows x 16 slots), linear dest;
    // source within-row byte = slot*16 ^ ((row&7)<<4)  (pre-swizzle, #21).
    auto stage = [&](int seg, int buf) {
        const char* srcb;
        size_t rstrideB, segoffB;
        if (seg < kBas) { srcb = (const char*)Gall; rstrideB = kBas * 256; segoffB = (size_t)seg * 256; }
        else            { srcb = (const char*)x;    rstrideB = 256;        segoffB = 0; }
#pragma unroll
        for (int it = 0; it < 2; ++it) {
            int gi = it * 256 + tid;
            int row = gi >> 4;
            int c = ((gi & 15) << 4) ^ ((row & 7) << 4);
            int gr = m0 + row;
            if (gr > M - 1) gr = M - 1;
            const char* src = srcb + (size_t)gr * rstrideB + segoffB + (size_t)c;
            unsigned short* ldst = &As[buf][0][0] + gi * 8;
            gload_lds16(src, ldst);
        }
    };

    f32x4 acc[2][2] = {};
    // prologue: stage segment 0, drain, barrier (+ publish fsh)
    stage(0, 0);
    __syncthreads();
    int cur = 0;
    for (int seg = 0; seg < kSeg; ++seg) {
        // B-loads FIRST (oldest in vmcnt queue -> their wait doesn't drain stage)
        const unsigned short* Bsrc = wallT + (size_t)seg * 16384;
        bf16x8 b[4][2];
#pragma unroll
        for (int kk4 = 0; kk4 < 4; ++kk4)
#pragma unroll
            for (int nt = 0; nt < 2; ++nt)
                b[kk4][nt] = *(const bf16x8*)(Bsrc + (size_t)(wn + nt * 16 + lrow) * 128
                                              + kk4 * 32 + lq * 8);
        __builtin_amdgcn_sched_barrier(0);   // pin: b-loads issue before stage
        if (seg < kSeg - 1) stage(seg + 1, cur ^ 1);
#pragma unroll
        for (int kk4 = 0; kk4 < 4; ++kk4) {
            bf16x8 a2[2];
#pragma unroll
            for (int mt = 0; mt < 2; ++mt) {
                int row = mt * 16 + lrow;
                int cb = (kk4 * 64 + lq * 16) ^ ((row & 7) << 4);
                a2[mt] = *(const bf16x8*)((const char*)&As[cur][0][0]
                                          + row * 256 + cb);
            }
#pragma unroll
            for (int mt = 0; mt < 2; ++mt)
#pragma unroll
                for (int nt = 0; nt < 2; ++nt)
                    acc[mt][nt] = __builtin_amdgcn_mfma_f32_16x16x32_bf16(
                        a2[mt], b[kk4][nt], acc[mt][nt], 0, 0, 0);
        }
        asm volatile("s_waitcnt vmcnt(0)" ::: "memory");
        __builtin_amdgcn_s_barrier();
        cur ^= 1;
    }

    // epilogue: +bias, row mean/var across 128 cols (4 waves x 32 cols), LN+ReLU
    const int f = fsh;
    float bv[2], gv[2], betav[2];
#pragma unroll
    for (int nt = 0; nt < 2; ++nt) {
        int gc = wn + nt * 16 + lrow;
        if (f) {
            bv[nt] = ((const float*)bias)[gc];
            gv[nt] = ((const float*)gw)[gc];
            betav[nt] = ((const float*)bw)[gc];
        } else {
            bv[nt] = bf2f_rg(((const unsigned short*)bias)[gc]);
            gv[nt] = bf2f_rg(((const unsigned short*)gw)[gc]);
            betav[nt] = bf2f_rg(((const unsigned short*)bw)[gc]);
        }
    }
#pragma unroll
    for (int mt = 0; mt < 2; ++mt)
#pragma unroll
        for (int i = 0; i < 4; ++i) {
            float sv = 0.f, qv = 0.f;
#pragma unroll
            for (int nt = 0; nt < 2; ++nt) {
                float v = acc[mt][nt][i] + bv[nt];
                acc[mt][nt][i] = v;
                sv += v;
                qv += v * v;
            }
            for (int o = 1; o < 16; o <<= 1) {
                sv += __shfl_xor(sv, o);
                qv += __shfl_xor(qv, o);
            }
            if (lrow == 0) {
                int row = mt * 16 + lq * 4 + i;
                pS[row][wave] = sv;
                pQ[row][wave] = qv;
            }
        }
    __syncthreads();
    if (tid < 32) {
        float s4 = pS[tid][0] + pS[tid][1] + pS[tid][2] + pS[tid][3];
        float q4 = pQ[tid][0] + pQ[tid][1] + pQ[tid][2] + pQ[tid][3];
        float mean = s4 * (1.0f / 128.0f);
        float var = q4 * (1.0f / 128.0f) - mean * mean;
        mrs[tid][0] = mean;
        mrs[tid][1] = rsqrtf(var + 1e-5f);
    }
    __syncthreads();
#pragma unroll
    for (int mt = 0; mt < 2; ++mt)
#pragma unroll
        for (int i = 0; i < 4; ++i) {
            int row = mt * 16 + lq * 4 + i;
            int gr = m0 + row;
            if (gr < M) {
                float mean = mrs[row][0];
                float rs = mrs[row][1];
#pragma unroll
                for (int nt = 0; nt < 2; ++nt) {
                    int gc = wn + nt * 16 + lrow;
                    float o = fmaxf((acc[mt][nt][i] - mean) * rs * gv[nt] + betav[nt], 0.f);
                    if (ofp32)
                        out_f[(size_t)gr * 128 + gc] = o;
                    else
                        out_b[(size_t)gr * 128 + gc] = f2bf_rg(o);
                }
            }
        }
}

extern "C" void kernel_launch(void* const* d_in, const int* in_sizes, int n_in,
                              void* d_out, int out_size, void* d_ws, size_t ws_size,
                              hipStream_t stream) {
    const int* ei = (const int*)d_in[0];            // [2,E] int32
    const int* et = (const int*)d_in[1];            // [E] int32
    const void* emb    = d_in[2];
    const void* bases1 = d_in[3];
    const void* coef1  = d_in[4];
    const void* selfw1 = d_in[5];
    const void* bias1  = d_in[6];
    const void* g1     = d_in[7];
    const void* b1     = d_in[8];
    const void* bases2 = d_in[9];
    const void* coef2  = d_in[10];
    const void* selfw2 = d_in[11];
    const void* bias2  = d_in[12];
    const void* g2     = d_in[13];
    const void* b2     = d_in[14];

    const int E = in_sizes[1];
    const int N = out_size / kDim;
    const int n16 = N * kRel;
    const int nsb = (n16 + 255) / 256;

    // workspace (256B-aligned). Gall = [N][1024] bf16 (102.4MB).
    char* ws = (char*)d_ws;
    size_t off = 0;
    float* coefw = (float*)(ws + off); off += 512;
    int* rowptr2 = (int*)(ws + off); off += (((size_t)n16 + 1) * 4 + 255) & ~(size_t)255;
    int* cnt     = (int*)(ws + off); off += ((size_t)n16 * 4 + 255) & ~(size_t)255;
    int* bsum    = (int*)(ws + off); off += ((size_t)nsb * 4 + 255) & ~(size_t)255;
    int* pcols   = (int*)(ws + off); off += ((size_t)E * 4 + 255) & ~(size_t)255;
    unsigned short* wallT = (unsigned short*)(ws + off);
    off += ((size_t)kSeg * 16384 * 2 + 255) & ~(size_t)255;
    unsigned short* xin  = (unsigned short*)(ws + off);
    off += ((size_t)N * 128 * 2 + 255) & ~(size_t)255;
    unsigned short* xmid = (unsigned short*)(ws + off);
    off += ((size_t)N * 128 * 2 + 255) & ~(size_t)255;
    unsigned short* Gall = (unsigned short*)(ws + off);
    (void)n_in; (void)ws_size;

    const int eblk = (E + 255) / 256;
    const int mblk32 = (N + 31) / 32;
    const int ablk = (N + 3) / 4;
    const int nelem = N * 128;
    const unsigned short* embh = (const unsigned short*)emb;

    // sentinel stub (template symbol; d_out fully overwritten by layer 2)
    RGCNEncoder_89962384982025_kernel<<<1, 256, 0, stream>>>((unsigned*)d_out, 256);

    // emb -> bf16 (dtype flag derived inline)
    cvt_rg<<<(nelem + 255) / 256, 256, 0, stream>>>(emb, xin, nelem);

    // CSR by (node, relation); in-place hierarchical scan
    zero_rg<<<(n16 + 255) / 256, 256, 0, stream>>>(cnt, n16);
    count_rg<<<eblk, 256, 0, stream>>>(ei, et, cnt, E);
    scanA_rg<<<nsb, 256, 0, stream>>>(cnt, rowptr2, bsum, n16);
    scanB_rg<<<1, 256, 0, stream>>>(bsum, nsb);
    scanC_rg<<<nsb, 256, 0, stream>>>(rowptr2, bsum, n16);
    fill_rg<<<eblk, 256, 0, stream>>>(ei, et, rowptr2, cnt, pcols, E);

    // layer 1: aggregate xin -> Gall (basis space), fused GEMM -> bf16 xmid
    wall_rg<<<kSeg * 64, 256, 0, stream>>>(bases1, coef1, selfw1, embh, wallT, coefw);
    agg2_rg<<<ablk, 256, 0, stream>>>(rowptr2, pcols, xin, coefw, Gall, N);
    fusegemm_rg<<<mblk32, 256, 0, stream>>>(Gall, xin, wallT, bias1, g1, b1, embh,
                                            xmid, (float*)nullptr, 0, N);

    // layer 2: aggregate xmid -> Gall, fused GEMM -> fp32 d_out
    wall_rg<<<kSeg * 64, 256, 0, stream>>>(bases2, coef2, selfw2, embh, wallT, coefw);
    agg2_rg<<<ablk, 256, 0, stream>>>(rowptr2, pcols, xmid, coefw, Gall, N);
    fusegemm_rg<<<mblk32, 256, 0, stream>>>(Gall, xmid, wallT, bias2, g2, b2, embh,
                                            (unsigned short*)nullptr, (float*)d_out,
                                            1, N);
}

// Round 10
// 374.487 us; speedup vs baseline: 1.1634x; 1.0866x over previous
//
#include <hip/hip_runtime.h>
#include <hip/hip_bf16.h>

// RGCN 2-layer encoder. N=50000, R=16, B=8, Dim=128, E=625000.
// fp32 in/out (runtime-detected), bf16 MFMA internals.
//
// R25: Gall segment-major. R24's occupancy theory failed (44% occ, WORSE
// dur): fusegemm is HBM-concurrency-bound on Gall reads at ~1TB/s because
// node-major [n][2048] makes each block's per-segment stage 64 discontiguous
// 256B slices at 2KB stride. Now Gall = [b][N][128] (segment-major): per
// segment a block stages one CONTIGUOUS 16KB run; consecutive blocks stream
// consecutive runs. agg2 writes stay 256B-coalesced (8 planes). fusegemm
// structure = R21's verified best (64-row tile, 2-phase dbuf, B-loads
// before stage w/ sched_barrier, both-sides XOR swizzle, lb(256,3)).
//
// Pipeline per layer: wallT[b][o][k]=bases[b]^T (slot8=selfw^T) + coefw fp32;
// agg2: wave-per-node CSR scan -> Gall[b][n][o] (basis space, 102MB);
// fusegemm: out[n][o] = [G(n) | x[n]] @ wallT (K=1152), epilogue LN+ReLU.

static constexpr int kDim = 128;
static constexpr int kRel = 16;
static constexpr int kBas = 8;
static constexpr int kSeg = kBas + 1;   // 8 bases + self

typedef __attribute__((ext_vector_type(8))) short bf16x8;
typedef __attribute__((ext_vector_type(4))) float f32x4;

static __device__ __forceinline__ float bf2f_rg(unsigned short h) {
    return __uint_as_float(((unsigned)h) << 16);
}
static __device__ __forceinline__ unsigned short f2bf_rg(float f) {
    unsigned u = __float_as_uint(f);
    u = u + 0x7fffu + ((u >> 16) & 1u);   // round-to-nearest-even
    return (unsigned short)(u >> 16);
}

static __device__ __forceinline__ void gload_lds16(const void* g, void* l) {
    __builtin_amdgcn_global_load_lds(
        (const __attribute__((address_space(1))) unsigned*)g,
        (__attribute__((address_space(3))) unsigned*)l, 16, 0, 0);
}

// dtype flag from emb's first 128 halves (call with one full wave, tid<64):
// any bf16-decoded exponent >= 0x86 (|v|>=128/inf/nan) => input is fp32
static __device__ __forceinline__ int flag_from(const unsigned short* x, int lane) {
    unsigned e0 = ((unsigned)x[lane] >> 7) & 0xFFu;
    unsigned e1 = ((unsigned)x[lane + 64] >> 7) & 0xFFu;
    int bad = (e0 >= 0x86u) || (e1 >= 0x86u);
    return (__ballot(bad) != 0ull) ? 1 : 0;
}

// template-named kernel: sentinel stub (d_out fully overwritten by pipeline)
__global__ void RGCNEncoder_89962384982025_kernel(unsigned* p, int n) {
    int i = blockIdx.x * 256 + threadIdx.x;
    if (i < n) p[i] = 0x3F803F80u;
}

// convert emb (fp32 or bf16, flag derived inline) -> bf16 xin
__global__ void cvt_rg(const void* xraw, unsigned short* xout, int n) {
    __shared__ int fsh;
    if (threadIdx.x < 64) {
        int fl = flag_from((const unsigned short*)xraw, threadIdx.x);
        if (threadIdx.x == 0) fsh = fl;
    }
    __syncthreads();
    int f = fsh;
    int i = blockIdx.x * 256 + threadIdx.x;
    if (i >= n) return;
    if (f)
        xout[i] = f2bf_rg(((const float*)xraw)[i]);
    else
        xout[i] = ((const unsigned short*)xraw)[i];
}

__global__ void zero_rg(int* p, int n) {
    int i = blockIdx.x * 256 + threadIdx.x;
    if (i < n) p[i] = 0;
}

__global__ void count_rg(const int* ei, const int* et, int* cnt, int E) {
    int e = blockIdx.x * 256 + threadIdx.x;
    if (e < E) atomicAdd(&cnt[ei[e] * kRel + et[e]], 1);
}

// hierarchical scan, in place on rowptr (saves the incl buffer)
__global__ void scanA_rg(const int* cnt, int* rowptr, int* bsum, int n) {
    __shared__ int sh[256];
    int tid = threadIdx.x;
    int i = blockIdx.x * 256 + tid;
    int v = (i < n) ? cnt[i] : 0;
    sh[tid] = v;
    __syncthreads();
    for (int off = 1; off < 256; off <<= 1) {
        int t = (tid >= off) ? sh[tid - off] : 0;
        __syncthreads();
        sh[tid] += t;
        __syncthreads();
    }
    if (i < n) rowptr[i + 1] = sh[tid];
    if (tid == 255) bsum[blockIdx.x] = sh[255];
}
__global__ void scanB_rg(int* bsum, int nb) {
    __shared__ int partial[256];
    int tid = threadIdx.x;
    int chunk = (nb + 255) / 256;
    int s0 = tid * chunk;
    int s1 = min(s0 + chunk, nb);
    int sum = 0;
    for (int i = s0; i < s1; ++i) sum += bsum[i];
    partial[tid] = sum;
    __syncthreads();
    for (int off = 1; off < 256; off <<= 1) {
        int t = (tid >= off) ? partial[tid - off] : 0;
        __syncthreads();
        partial[tid] += t;
        __syncthreads();
    }
    int run = (tid == 0) ? 0 : partial[tid - 1];
    for (int i = s0; i < s1; ++i) { int v = bsum[i]; bsum[i] = run; run += v; }
}
__global__ void scanC_rg(int* rowptr, const int* bsum, int n) {
    int i = blockIdx.x * 256 + threadIdx.x;
    if (i < n) rowptr[i + 1] += bsum[blockIdx.x];
    if (i == 0) rowptr[0] = 0;
}

// fill: pcols entry packs col | rel<<26 (col < 2^26)
__global__ void fill_rg(const int* ei, const int* et, const int* rowptr,
                        int* cnt, int* pcols, int E) {
    int e = blockIdx.x * 256 + threadIdx.x;
    if (e < E) {
        int rel = et[e];
        int key = ei[e] * kRel + rel;
        int old = atomicSub(&cnt[key], 1);
        pcols[rowptr[key] + old - 1] = ei[E + e] | (rel << 26);
    }
}

// wallT[b][o][k] = bases[b][k][o] for b<8; slot 8 = selfw^T.
// Also stages coef decoded to fp32 (coefw[16][8]) for agg2's LDS mix table.
__global__ void wall_rg(const void* bases, const void* coef, const void* selfw,
                        const unsigned short* emb, unsigned short* wallT,
                        float* coefw) {
    __shared__ int fsh;
    if (threadIdx.x < 64) {
        int fl = flag_from(emb, threadIdx.x);
        if (threadIdx.x == 0) fsh = fl;
    }
    __syncthreads();
    int f = fsh;
    int idx = blockIdx.x * 256 + threadIdx.x;   // b*16384 + o*128 + k
    int b = idx >> 14;
    int o = (idx >> 7) & 127;
    int k = idx & 127;
    if (blockIdx.x == 0 && threadIdx.x < kRel * kBas) {
        coefw[threadIdx.x] = f ? ((const float*)coef)[threadIdx.x]
                               : bf2f_rg(((const unsigned short*)coef)[threadIdx.x]);
    }
    if (b < kBas) {
        float bv = f ? ((const float*)bases)[b * 16384 + k * 128 + o]
                     : bf2f_rg(((const unsigned short*)bases)[b * 16384 + k * 128 + o]);
        wallT[idx] = f2bf_rg(bv);
    } else {
        float sv = f ? ((const float*)selfw)[k * 128 + o]
                     : bf2f_rg(((const unsigned short*)selfw)[k * 128 + o]);
        wallT[idx] = f2bf_rg(sv);
    }
}

// aggregate-first in basis space: Gall[b][n][o] = sum_r coefw[r][b] *
// mean over r-bucket edges of x[col][o]. Wave per node (4 waves/block).
// Depth-4 batched gather: 4 readlanes + 4 independent loads in flight,
// then bucket-transition logic on the returned values (latency overlap).
// Writes: per b one contiguous 256B chunk at plane offset b*N*256.
__global__ __launch_bounds__(256) void agg2_rg(const int* rowptr2, const int* pcols,
                                               const unsigned short* xsrc,
                                               const float* coefw,
                                               unsigned short* Gall, int N) {
    __shared__ float csh[kRel * kBas];
    if (threadIdx.x < kRel * kBas) csh[threadIdx.x] = coefw[threadIdx.x];
    __syncthreads();
    int wv = threadIdx.x >> 6;
    int lane = threadIdx.x & 63;
    int n = blockIdx.x * 4 + wv;
    if (n >= N) return;
    const int s = rowptr2[n * kRel];          // wave-uniform -> scalar load
    const int e = rowptr2[n * kRel + kRel];
    const unsigned short* xl = xsrc + 2 * lane;
    float g0[kBas], g1[kBas];
#pragma unroll
    for (int b = 0; b < kBas; ++b) { g0[b] = 0.f; g1[b] = 0.f; }
    float s0 = 0.f, s1 = 0.f;
    int cur = -1, cnt = 0;
    auto flush = [&]() {
        float w = __builtin_amdgcn_rcpf((float)cnt);
        float t0 = s0 * w, t1 = s1 * w;
        const float* cr = csh + cur * kBas;
#pragma unroll
        for (int b = 0; b < kBas; ++b) {
            float c = cr[b];                  // broadcast ds_read
            g0[b] += c * t0;
            g1[b] += c * t1;
        }
        s0 = 0.f; s1 = 0.f; cnt = 0;
    };
    for (int base = s; base < e; base += 64) {
        int m = e - base;
        if (m > 64) m = 64;
        int pk = 0;
        if (base + lane < e) pk = pcols[base + lane];
        int i = 0;
        for (; i + 4 <= m; i += 4) {
            // issue 4 independent gathers back-to-back (4 in flight)
            int v0 = __builtin_amdgcn_readlane(pk, i);
            int v1 = __builtin_amdgcn_readlane(pk, i + 1);
            int v2 = __builtin_amdgcn_readlane(pk, i + 2);
            int v3 = __builtin_amdgcn_readlane(pk, i + 3);
            unsigned u0 = *(const unsigned*)(xl + (size_t)(v0 & 0x03FFFFFF) * 128);
            unsigned u1 = *(const unsigned*)(xl + (size_t)(v1 & 0x03FFFFFF) * 128);
            unsigned u2 = *(const unsigned*)(xl + (size_t)(v2 & 0x03FFFFFF) * 128);
            unsigned u3 = *(const unsigned*)(xl + (size_t)(v3 & 0x03FFFFFF) * 128);
            int r0 = (int)((unsigned)v0 >> 26);
            int r1 = (int)((unsigned)v1 >> 26);
            int r2 = (int)((unsigned)v2 >> 26);
            int r3 = (int)((unsigned)v3 >> 26);
            if (r0 != cur) { if (cnt) flush(); cur = r0; }
            s0 += __uint_as_float(u0 << 16); s1 += __uint_as_float(u0 & 0xffff0000u); ++cnt;
            if (r1 != cur) { flush(); cur = r1; }
            s0 += __uint_as_float(u1 << 16); s1 += __uint_as_float(u1 & 0xffff0000u); ++cnt;
            if (r2 != cur) { flush(); cur = r2; }
            s0 += __uint_as_float(u2 << 16); s1 += __uint_as_float(u2 & 0xffff0000u); ++cnt;
            if (r3 != cur) { flush(); cur = r3; }
            s0 += __uint_as_float(u3 << 16); s1 += __uint_as_float(u3 & 0xffff0000u); ++cnt;
        }
        for (; i < m; ++i) {
            int v = __builtin_amdgcn_readlane(pk, i);
            unsigned u = *(const unsigned*)(xl + (size_t)(v & 0x03FFFFFF) * 128);
            int rel = (int)((unsigned)v >> 26);
            if (rel != cur) { if (cnt) flush(); cur = rel; }
            s0 += __uint_as_float(u << 16);
            s1 += __uint_as_float(u & 0xffff0000u);
            ++cnt;
        }
    }
    if (cnt) flush();
    unsigned short* grow = Gall + (size_t)n * 128 + 2 * lane;
    const size_t plane = (size_t)N * 128;
#pragma unroll
    for (int b = 0; b < kBas; ++b) {
        unsigned outp = (unsigned)f2bf_rg(g0[b]) | ((unsigned)f2bf_rg(g1[b]) << 16);
        *(unsigned*)(grow + (size_t)b * plane) = outp;
    }
}

// fused GEMM: out[n][o] = [G(n) (K=1024) | x[n] (K=128)] @ wallT[seg][o][k]
// + bias, then LayerNorm + ReLU in-epilogue. 64-row C-tile, 4 waves each
// owning a 64x32 column slice (16x16x32 bf16 MFMA; C map m89/m91:
// col=lane&15, row=(lane>>4)*4+reg). Double-buffered global_load_lds A-tile
// with row-XOR swizzle (both-sides); per segment: B-loads FIRST (oldest in
// vmcnt queue), then stage(seg+1), then ds_read+MFMA, then vmcnt(0)+barrier.
// Segment-major Gall: each stage reads a contiguous 16KB run.
__global__ __launch_bounds__(256, 3) void fusegemm_rg(const unsigned short* Gall,
                                                      const unsigned short* x,
                                                      const unsigned short* wallT,
                                                      const void* bias, const void* gw,
                                                      const void* bw,
                                                      const unsigned short* emb,
                                                      unsigned short* out_b, float* out_f,
                                                      int ofp32, int M) {
    __shared__ __align__(16) unsigned short As[2][64][128];   // linear, swizzled
    __shared__ float pS[64][5];
    __shared__ float pQ[64][5];
    __shared__ float mrs[64][2];
    __shared__ int fsh;
    const int m0 = blockIdx.x * 64;
    const int tid = threadIdx.x;
    const int wave = tid >> 6;
    const int lane = tid & 63;
    const int wn = wave * 32;
    const int lrow = lane & 15;
    const int lq = lane >> 4;
    if (tid < 64) {
        int fl = flag_from(emb, tid);
        if (tid == 0) fsh = fl;
    }

    // stage segment seg into As[buf]: 4 x global_load_lds(16B) per thread.
    // granule gi=(wave*4+it)*64+lane: row=gi>>4, slot=gi&15, linear dest;
    // source within-row byte = slot*16 ^ ((row&7)<<4)  (pre-swizzle, #21).
    // All segments have row stride 256B (segment-major planes / x).
    auto stage = [&](int seg, int buf) {
        const char* srcb = (seg < kBas)
            ? (const char*)(Gall + (size_t)seg * M * 128)
            : (const char*)x;
#pragma unroll
        for (int it = 0; it < 4; ++it) {
            int gi = (wave * 4 + it) * 64 + lane;
            int row = gi >> 4;
            int c = ((gi & 15) << 4) ^ ((row & 7) << 4);
            int gr = m0 + row;
            if (gr > M - 1) gr = M - 1;
            const char* src = srcb + (size_t)gr * 256 + (size_t)c;
            unsigned short* ldst = &As[buf][0][0] + ((wave * 4 + it) << 9);
            gload_lds16(src, ldst);
        }
    };

    f32x4 acc[4][2] = {};
    // prologue: stage segment 0, drain + publish fsh
    stage(0, 0);
    __syncthreads();
    int cur = 0;
    for (int seg = 0; seg < kSeg; ++seg) {
        // B-loads FIRST (oldest in vmcnt queue -> their wait doesn't drain stage)
        const unsigned short* Bsrc = wallT + (size_t)seg * 16384;
        bf16x8 b[4][2];
#pragma unroll
        for (int kk4 = 0; kk4 < 4; ++kk4)
#pragma unroll
            for (int nt = 0; nt < 2; ++nt)
                b[kk4][nt] = *(const bf16x8*)(Bsrc + (size_t)(wn + nt * 16 + lrow) * 128
                                              + kk4 * 32 + lq * 8);
        __builtin_amdgcn_sched_barrier(0);   // pin: b-loads issue before stage
        if (seg < kSeg - 1) stage(seg + 1, cur ^ 1);
#pragma unroll
        for (int kk4 = 0; kk4 < 4; ++kk4) {
            bf16x8 a4[4];
#pragma unroll
            for (int mt = 0; mt < 4; ++mt) {
                int row = mt * 16 + lrow;
                int cb = (kk4 * 64 + lq * 16) ^ ((row & 7) << 4);
                a4[mt] = *(const bf16x8*)((const char*)&As[cur][0][0]
                                          + row * 256 + cb);
            }
#pragma unroll
            for (int mt = 0; mt < 4; ++mt)
#pragma unroll
                for (int nt = 0; nt < 2; ++nt)
                    acc[mt][nt] = __builtin_amdgcn_mfma_f32_16x16x32_bf16(
                        a4[mt], b[kk4][nt], acc[mt][nt], 0, 0, 0);
        }
        asm volatile("s_waitcnt vmcnt(0)" ::: "memory");
        __builtin_amdgcn_s_barrier();
        cur ^= 1;
    }

    // epilogue: +bias, row mean/var across 128 cols (4 waves x 32 cols), LN+ReLU
    const int f = fsh;
    float bv[2], gv[2], betav[2];
#pragma unroll
    for (int nt = 0; nt < 2; ++nt) {
        int gc = wn + nt * 16 + lrow;
        if (f) {
            bv[nt] = ((const float*)bias)[gc];
            gv[nt] = ((const float*)gw)[gc];
            betav[nt] = ((const float*)bw)[gc];
        } else {
            bv[nt] = bf2f_rg(((const unsigned short*)bias)[gc]);
            gv[nt] = bf2f_rg(((const unsigned short*)gw)[gc]);
            betav[nt] = bf2f_rg(((const unsigned short*)bw)[gc]);
        }
    }
#pragma unroll
    for (int mt = 0; mt < 4; ++mt)
#pragma unroll
        for (int i = 0; i < 4; ++i) {
            float sv = 0.f, qv = 0.f;
#pragma unroll
            for (int nt = 0; nt < 2; ++nt) {
                float v = acc[mt][nt][i] + bv[nt];
                acc[mt][nt][i] = v;
                sv += v;
                qv += v * v;
            }
            for (int o = 1; o < 16; o <<= 1) {
                sv += __shfl_xor(sv, o);
                qv += __shfl_xor(qv, o);
            }
            if (lrow == 0) {
                int row = mt * 16 + lq * 4 + i;
                pS[row][wave] = sv;
                pQ[row][wave] = qv;
            }
        }
    __syncthreads();
    if (tid < 64) {
        float s4 = pS[tid][0] + pS[tid][1] + pS[tid][2] + pS[tid][3];
        float q4 = pQ[tid][0] + pQ[tid][1] + pQ[tid][2] + pQ[tid][3];
        float mean = s4 * (1.0f / 128.0f);
        float var = q4 * (1.0f / 128.0f) - mean * mean;
        mrs[tid][0] = mean;
        mrs[tid][1] = rsqrtf(var + 1e-5f);
    }
    __syncthreads();
#pragma unroll
    for (int mt = 0; mt < 4; ++mt)
#pragma unroll
        for (int i = 0; i < 4; ++i) {
            int row = mt * 16 + lq * 4 + i;
            int gr = m0 + row;
            if (gr < M) {
                float mean = mrs[row][0];
                float rs = mrs[row][1];
#pragma unroll
                for (int nt = 0; nt < 2; ++nt) {
                    int gc = wn + nt * 16 + lrow;
                    float o = fmaxf((acc[mt][nt][i] - mean) * rs * gv[nt] + betav[nt], 0.f);
                    if (ofp32)
                        out_f[(size_t)gr * 128 + gc] = o;
                    else
                        out_b[(size_t)gr * 128 + gc] = f2bf_rg(o);
                }
            }
        }
}

extern "C" void kernel_launch(void* const* d_in, const int* in_sizes, int n_in,
                              void* d_out, int out_size, void* d_ws, size_t ws_size,
                              hipStream_t stream) {
    const int* ei = (const int*)d_in[0];            // [2,E] int32
    const int* et = (const int*)d_in[1];            // [E] int32
    const void* emb    = d_in[2];
    const void* bases1 = d_in[3];
    const void* coef1  = d_in[4];
    const void* selfw1 = d_in[5];
    const void* bias1  = d_in[6];
    const void* g1     = d_in[7];
    const void* b1     = d_in[8];
    const void* bases2 = d_in[9];
    const void* coef2  = d_in[10];
    const void* selfw2 = d_in[11];
    const void* bias2  = d_in[12];
    const void* g2     = d_in[13];
    const void* b2     = d_in[14];

    const int E = in_sizes[1];
    const int N = out_size / kDim;
    const int n16 = N * kRel;
    const int nsb = (n16 + 255) / 256;

    // workspace (256B-aligned). Gall = [8][N][128] bf16 (102.4MB, seg-major).
    char* ws = (char*)d_ws;
    size_t off = 0;
    float* coefw = (float*)(ws + off); off += 512;
    int* rowptr2 = (int*)(ws + off); off += (((size_t)n16 + 1) * 4 + 255) & ~(size_t)255;
    int* cnt     = (int*)(ws + off); off += ((size_t)n16 * 4 + 255) & ~(size_t)255;
    int* bsum    = (int*)(ws + off); off += ((size_t)nsb * 4 + 255) & ~(size_t)255;
    int* pcols   = (int*)(ws + off); off += ((size_t)E * 4 + 255) & ~(size_t)255;
    unsigned short* wallT = (unsigned short*)(ws + off);
    off += ((size_t)kSeg * 16384 * 2 + 255) & ~(size_t)255;
    unsigned short* xin  = (unsigned short*)(ws + off);
    off += ((size_t)N * 128 * 2 + 255) & ~(size_t)255;
    unsigned short* xmid = (unsigned short*)(ws + off);
    off += ((size_t)N * 128 * 2 + 255) & ~(size_t)255;
    unsigned short* Gall = (unsigned short*)(ws + off);
    (void)n_in; (void)ws_size;

    const int eblk = (E + 255) / 256;
    const int mblk64 = (N + 63) / 64;
    const int ablk = (N + 3) / 4;
    const int nelem = N * 128;
    const unsigned short* embh = (const unsigned short*)emb;

    // sentinel stub (template symbol; d_out fully overwritten by layer 2)
    RGCNEncoder_89962384982025_kernel<<<1, 256, 0, stream>>>((unsigned*)d_out, 256);

    // emb -> bf16 (dtype flag derived inline)
    cvt_rg<<<(nelem + 255) / 256, 256, 0, stream>>>(emb, xin, nelem);

    // CSR by (node, relation); in-place hierarchical scan
    zero_rg<<<(n16 + 255) / 256, 256, 0, stream>>>(cnt, n16);
    count_rg<<<eblk, 256, 0, stream>>>(ei, et, cnt, E);
    scanA_rg<<<nsb, 256, 0, stream>>>(cnt, rowptr2, bsum, n16);
    scanB_rg<<<1, 256, 0, stream>>>(bsum, nsb);
    scanC_rg<<<nsb, 256, 0, stream>>>(rowptr2, bsum, n16);
    fill_rg<<<eblk, 256, 0, stream>>>(ei, et, rowptr2, cnt, pcols, E);

    // layer 1: aggregate xin -> Gall (basis space), fused GEMM -> bf16 xmid
    wall_rg<<<kSeg * 64, 256, 0, stream>>>(bases1, coef1, selfw1, embh, wallT, coefw);
    agg2_rg<<<ablk, 256, 0, stream>>>(rowptr2, pcols, xin, coefw, Gall, N);
    fusegemm_rg<<<mblk64, 256, 0, stream>>>(Gall, xin, wallT, bias1, g1, b1, embh,
                                            xmid, (float*)nullptr, 0, N);

    // layer 2: aggregate xmid -> Gall, fused GEMM -> fp32 d_out
    wall_rg<<<kSeg * 64, 256, 0, stream>>>(bases2, coef2, selfw2, embh, wallT, coefw);
    agg2_rg<<<ablk, 256, 0, stream>>>(rowptr2, pcols, xmid, coefw, Gall, N);
    fusegemm_rg<<<mblk64, 256, 0, stream>>>(Gall, xmid, wallT, bias2, g2, b2, embh,
                                            (unsigned short*)nullptr, (float*)d_out,
                                            1, N);
}